// Round 2
// baseline (925.085 us; speedup 1.0000x reference)
//
#include <hip/hip_runtime.h>
#include <math.h>

// ---- static config ----
// NS=16, NV=4, C=32, RDIM=32, FC_DIM=64, WNUM=416, L=2
#define SQRT3f     1.7320508075688772f
#define INV_SQRT3f 0.5773502691896258f
#define INV_SQRT2f 0.7071067811865476f
#define A0f        0.22360679774997896f   // 1/sqrt(16+4)
#define A1f        0.20412414523193150f   // 1/sqrt(16+8)

__device__ __forceinline__ float4 ld4(const float* p) {
    return *reinterpret_cast<const float4*>(p);
}

// out[16] = in[16] @ W[16,16] + b ; optional relu
template<bool RELU>
__device__ __forceinline__ void mm16x16(const float* in, const float* __restrict__ W,
                                        const float* __restrict__ b, float* out)
{
#pragma unroll
    for (int t = 0; t < 16; ++t) out[t] = b[t];
#pragma unroll
    for (int s = 0; s < 16; ++s) {
        float a = in[s];
#pragma unroll
        for (int q = 0; q < 4; ++q) {
            float4 w = ld4(W + s * 16 + q * 4);
            out[q*4+0] += a * w.x; out[q*4+1] += a * w.y;
            out[q*4+2] += a * w.z; out[q*4+3] += a * w.w;
        }
    }
    if (RELU) {
#pragma unroll
        for (int t = 0; t < 16; ++t) out[t] = fmaxf(out[t], 0.f);
    }
}

// h0[n] = MLP(node_feats[n] @ enc_W + enc_b)
__global__ __launch_bounds__(256)
void node_embed_kernel(const float* __restrict__ nf,
                       const float* __restrict__ encW, const float* __restrict__ encb,
                       const float* __restrict__ neW1, const float* __restrict__ neb1,
                       const float* __restrict__ neW2, const float* __restrict__ neb2,
                       float* __restrict__ h0, int N)
{
    int n = blockIdx.x * blockDim.x + threadIdx.x;
    if (n >= N) return;
    float x[16];
#pragma unroll
    for (int s = 0; s < 16; ++s) x[s] = encb[s];
    for (int i = 0; i < 64; ++i) {
        float a = nf[n * 64 + i];
#pragma unroll
        for (int q = 0; q < 4; ++q) {
            float4 w = ld4(encW + i * 16 + q * 4);
            x[q*4+0] += a * w.x; x[q*4+1] += a * w.y;
            x[q*4+2] += a * w.z; x[q*4+3] += a * w.w;
        }
    }
    float h[16], o[16];
    mm16x16<true >(x, neW1, neb1, h);
    mm16x16<false>(h, neW2, neb2, o);
#pragma unroll
    for (int j = 0; j < 16; ++j) h0[n * 16 + j] = o[j];
}

// per-edge: y1, edge_attr = MLP(edge_attr_in) + MLP(rbf(d)), cnt scatter
__global__ __launch_bounds__(256)
void edge_pre_kernel(const float* __restrict__ pos, const float* __restrict__ eain,
                     const int* __restrict__ srcI, const int* __restrict__ dstI,
                     const float* __restrict__ eeW1, const float* __restrict__ eeb1,
                     const float* __restrict__ eeW2, const float* __restrict__ eeb2,
                     const float* __restrict__ reW1, const float* __restrict__ reb1,
                     const float* __restrict__ reW2, const float* __restrict__ reb2,
                     float* __restrict__ eattr, float* __restrict__ y1g,
                     float* __restrict__ cnt, int E)
{
    int e = blockIdx.x * blockDim.x + threadIdx.x;
    if (e >= E) return;
    int s = srcI[e], d = dstI[e];
    float vx = pos[s*3+0] - pos[d*3+0];
    float vy = pos[s*3+1] - pos[d*3+1];
    float vz = pos[s*3+2] - pos[d*3+2];
    float dist = sqrtf(vx*vx + vy*vy + vz*vz);
    float inv = 1.f / fmaxf(dist, 1e-9f);
    y1g[e*3+0] = SQRT3f * vx * inv;
    y1g[e*3+1] = SQRT3f * vy * inv;
    y1g[e*3+2] = SQRT3f * vz * inv;

    // GaussianSmearing: offsets j*(12/31), coeff = -0.5/step^2
    const float step  = 12.0f / 31.0f;
    const float coeff = -0.5f / (step * step);
    float rbf[32];
#pragma unroll
    for (int j = 0; j < 32; ++j) {
        float t = dist - (float)j * step;
        rbf[j] = expf(coeff * t * t);
    }

    float ein[16];
#pragma unroll
    for (int j = 0; j < 16; ++j) ein[j] = eain[e * 16 + j];

    float t1[16], a1v[16];
    mm16x16<true >(ein, eeW1, eeb1, t1);
    mm16x16<false>(t1, eeW2, eeb2, a1v);

    float t2[16];
#pragma unroll
    for (int t = 0; t < 16; ++t) t2[t] = reb1[t];
    for (int j = 0; j < 32; ++j) {
        float a = rbf[j];
#pragma unroll
        for (int q = 0; q < 4; ++q) {
            float4 w = ld4(reW1 + j * 16 + q * 4);
            t2[q*4+0] += a * w.x; t2[q*4+1] += a * w.y;
            t2[q*4+2] += a * w.z; t2[q*4+3] += a * w.w;
        }
    }
#pragma unroll
    for (int t = 0; t < 16; ++t) t2[t] = fmaxf(t2[t], 0.f);
    float a2v[16];
    mm16x16<false>(t2, reW2, reb2, a2v);

#pragma unroll
    for (int j = 0; j < 16; ++j) eattr[e * 16 + j] = a1v[j] + a2v[j];

    atomicAdd(&cnt[s], 1.0f);
}

// fused: per-edge TP-weight MLP + tensor product + scatter into acc (sum;
// the /cnt mean happens once, in node_update_kernel)
template<bool HAS_L1>
__global__ __launch_bounds__(256)
void edge_tp_kernel(const float* __restrict__ h0, const float* __restrict__ h1,
                    const float* __restrict__ eattr, const float* __restrict__ y1g,
                    const int* __restrict__ srcI, const int* __restrict__ dstI,
                    const float* __restrict__ fc1W, const float* __restrict__ fc1b,
                    const float* __restrict__ fc2W, const float* __restrict__ fc2b,
                    float* __restrict__ acc0, float* __restrict__ acc1, int E)
{
    int e = blockIdx.x * blockDim.x + threadIdx.x;
    if (e >= E) return;
    int s = srcI[e], d = dstI[e];

    // ea = [edge_attr | h0[src] | h0[dst]]
    float ea[48];
#pragma unroll
    for (int q = 0; q < 4; ++q) {
        float4 v = ld4(eattr + e * 16 + q * 4);
        ea[q*4+0] = v.x; ea[q*4+1] = v.y; ea[q*4+2] = v.z; ea[q*4+3] = v.w;
    }
#pragma unroll
    for (int q = 0; q < 4; ++q) {
        float4 v = ld4(h0 + s * 16 + q * 4);
        ea[16+q*4+0] = v.x; ea[16+q*4+1] = v.y; ea[16+q*4+2] = v.z; ea[16+q*4+3] = v.w;
    }
#pragma unroll
    for (int q = 0; q < 4; ++q) {
        float4 v = ld4(h0 + d * 16 + q * 4);
        ea[32+q*4+0] = v.x; ea[32+q*4+1] = v.y; ea[32+q*4+2] = v.z; ea[32+q*4+3] = v.w;
    }

    // hid = relu(ea @ fc1W + fc1b), fc1W [48,64]
    float hid[64];
#pragma unroll
    for (int k = 0; k < 64; ++k) hid[k] = fc1b[k];
    for (int j = 0; j < 48; ++j) {
        float a = ea[j];
#pragma unroll
        for (int q = 0; q < 16; ++q) {
            float4 w = ld4(fc1W + j * 64 + q * 4);
            hid[q*4+0] += a * w.x; hid[q*4+1] += a * w.y;
            hid[q*4+2] += a * w.z; hid[q*4+3] += a * w.w;
        }
    }
#pragma unroll
    for (int k = 0; k < 64; ++k) hid[k] = fmaxf(hid[k], 0.f);

    float x0[16];
#pragma unroll
    for (int j = 0; j < 16; ++j) x0[j] = ea[32 + j];

    float yv0 = y1g[e*3+0], yv1 = y1g[e*3+1], yv2 = y1g[e*3+2];

    float x1v[4][3], dotv[4], crv[4][3];
    if (HAS_L1) {
#pragma unroll
        for (int v = 0; v < 4; ++v) {
            x1v[v][0] = h1[d*12 + v*3 + 0];
            x1v[v][1] = h1[d*12 + v*3 + 1];
            x1v[v][2] = h1[d*12 + v*3 + 2];
            dotv[v] = (x1v[v][0]*yv0 + x1v[v][1]*yv1 + x1v[v][2]*yv2) * INV_SQRT3f;
            crv[v][0] = (x1v[v][1]*yv2 - x1v[v][2]*yv1) * INV_SQRT2f;
            crv[v][1] = (x1v[v][2]*yv0 - x1v[v][0]*yv2) * INV_SQRT2f;
            crv[v][2] = (x1v[v][0]*yv1 - x1v[v][1]*yv0) * INV_SQRT2f;
        }
    }

    float o0[16];
#pragma unroll
    for (int o = 0; o < 16; ++o) o0[o] = 0.f;
    float t011[4] = {0.f, 0.f, 0.f, 0.f};
    float o1[4][3] = {};

    // ---- w00 block: j = n*16+o (fc2 cols 0..255): o0 += x0[n]*w00[n,:]
    for (int n = 0; n < 16; ++n) {
        float wrow[16];
#pragma unroll
        for (int q = 0; q < 4; ++q) {
            float4 b4 = ld4(fc2b + n * 16 + q * 4);
            wrow[q*4+0] = b4.x; wrow[q*4+1] = b4.y; wrow[q*4+2] = b4.z; wrow[q*4+3] = b4.w;
        }
        for (int k = 0; k < 64; ++k) {
            float hk = hid[k];
#pragma unroll
            for (int q = 0; q < 4; ++q) {
                float4 w4 = ld4(fc2W + k * 416 + n * 16 + q * 4);
                wrow[q*4+0] += hk * w4.x; wrow[q*4+1] += hk * w4.y;
                wrow[q*4+2] += hk * w4.z; wrow[q*4+3] += hk * w4.w;
            }
        }
        float xn = x0[n];
#pragma unroll
        for (int o = 0; o < 16; ++o) o0[o] += xn * wrow[o];
    }

    // ---- w011 block: cols 256..319 [16,4]: t011[o] = sum_n x0[n]*w011[n,o]
    for (int n = 0; n < 16; ++n) {
        float4 b4 = ld4(fc2b + 256 + n * 4);
        float w0 = b4.x, w1 = b4.y, w2 = b4.z, w3 = b4.w;
        for (int k = 0; k < 64; ++k) {
            float hk = hid[k];
            float4 w4 = ld4(fc2W + k * 416 + 256 + n * 4);
            w0 += hk * w4.x; w1 += hk * w4.y; w2 += hk * w4.z; w3 += hk * w4.w;
        }
        float xn = x0[n];
        t011[0] += xn * w0; t011[1] += xn * w1; t011[2] += xn * w2; t011[3] += xn * w3;
    }

    if (HAS_L1) {
        // ---- w101 block: cols 320..335 [4,4]: o1[o,m] += sum_n x1[n,m]*w101[n,o]
        for (int n = 0; n < 4; ++n) {
            float4 b4 = ld4(fc2b + 320 + n * 4);
            float w0 = b4.x, w1 = b4.y, w2 = b4.z, w3 = b4.w;
            for (int k = 0; k < 64; ++k) {
                float hk = hid[k];
                float4 w4 = ld4(fc2W + k * 416 + 320 + n * 4);
                w0 += hk * w4.x; w1 += hk * w4.y; w2 += hk * w4.z; w3 += hk * w4.w;
            }
#pragma unroll
            for (int m = 0; m < 3; ++m) {
                float xm = x1v[n][m];
                o1[0][m] += xm * w0; o1[1][m] += xm * w1;
                o1[2][m] += xm * w2; o1[3][m] += xm * w3;
            }
        }
        // ---- w110 block: cols 336..399 [4,16]: o0[o] += dot[n]*w110[n,o]
        for (int n = 0; n < 4; ++n) {
            float wrow[16];
#pragma unroll
            for (int q = 0; q < 4; ++q) {
                float4 b4 = ld4(fc2b + 336 + n * 16 + q * 4);
                wrow[q*4+0] = b4.x; wrow[q*4+1] = b4.y; wrow[q*4+2] = b4.z; wrow[q*4+3] = b4.w;
            }
            for (int k = 0; k < 64; ++k) {
                float hk = hid[k];
#pragma unroll
                for (int q = 0; q < 4; ++q) {
                    float4 w4 = ld4(fc2W + k * 416 + 336 + n * 16 + q * 4);
                    wrow[q*4+0] += hk * w4.x; wrow[q*4+1] += hk * w4.y;
                    wrow[q*4+2] += hk * w4.z; wrow[q*4+3] += hk * w4.w;
                }
            }
            float dn = dotv[n];
#pragma unroll
            for (int o = 0; o < 16; ++o) o0[o] += dn * wrow[o];
        }
        // ---- w111 block: cols 400..415 [4,4]: o1[o,m] += sum_n cr[n,m]*w111[n,o]
        for (int n = 0; n < 4; ++n) {
            float4 b4 = ld4(fc2b + 400 + n * 4);
            float w0 = b4.x, w1 = b4.y, w2 = b4.z, w3 = b4.w;
            for (int k = 0; k < 64; ++k) {
                float hk = hid[k];
                float4 w4 = ld4(fc2W + k * 416 + 400 + n * 4);
                w0 += hk * w4.x; w1 += hk * w4.y; w2 += hk * w4.z; w3 += hk * w4.w;
            }
#pragma unroll
            for (int m = 0; m < 3; ++m) {
                float cm = crv[n][m];
                o1[0][m] += cm * w0; o1[1][m] += cm * w1;
                o1[2][m] += cm * w2; o1[3][m] += cm * w3;
            }
        }
    }

    // o1 += t011[o] * y1[m]
#pragma unroll
    for (int o = 0; o < 4; ++o) {
        o1[o][0] += t011[o] * yv0;
        o1[o][1] += t011[o] * yv1;
        o1[o][2] += t011[o] * yv2;
    }

#pragma unroll
    for (int o = 0; o < 16; ++o) atomicAdd(&acc0[s * 16 + o], A0f * o0[o]);
#pragma unroll
    for (int o = 0; o < 4; ++o) {
#pragma unroll
        for (int m = 0; m < 3; ++m) atomicAdd(&acc1[s * 12 + o * 3 + m], A1f * o1[o][m]);
    }
}

// residual update: h += acc / max(cnt,1)   (the single scatter-MEAN divide)
__global__ void node_update_kernel(float* __restrict__ h0, float* __restrict__ h1,
                                   const float* __restrict__ acc0, const float* __restrict__ acc1,
                                   const float* __restrict__ cnt, int N)
{
    int j = threadIdx.x;                       // 0..31 (use 0..27)
    int n = blockIdx.x * blockDim.y + threadIdx.y;
    if (n >= N || j >= 28) return;
    float invc = 1.f / fmaxf(cnt[n], 1.f);
    if (j < 16) h0[n * 16 + j] += acc0[n * 16 + j] * invc;
    else {
        int m = j - 16;
        h1[n * 12 + m] += acc1[n * 12 + m] * invc;
    }
}

// final o3.Linear + sorter: out[n, c*4+0]=f0[n,c]; out[n, c*4+1+m]=f1[n,c,m]
__global__ __launch_bounds__(256)
void final_kernel(const float* __restrict__ h0, const float* __restrict__ h1,
                  const float* __restrict__ lin0, const float* __restrict__ lin1,
                  float* __restrict__ out, int N)
{
    int i = blockIdx.x * blockDim.x + threadIdx.x;
    if (i >= N * 32) return;
    int n = i >> 5, c = i & 31;
    float f0 = 0.f;
#pragma unroll
    for (int s = 0; s < 16; ++s) f0 += h0[n * 16 + s] * lin0[s * 32 + c];
    f0 *= 0.25f;                                // 1/sqrt(16)
    float f1x = 0.f, f1y = 0.f, f1z = 0.f;
#pragma unroll
    for (int v = 0; v < 4; ++v) {
        float w = lin1[v * 32 + c];
        f1x += h1[n * 12 + v * 3 + 0] * w;
        f1y += h1[n * 12 + v * 3 + 1] * w;
        f1z += h1[n * 12 + v * 3 + 2] * w;
    }
    float4 r;
    r.x = f0;
    r.y = f1x * 0.5f;                           // 1/sqrt(4)
    r.z = f1y * 0.5f;
    r.w = f1z * 0.5f;
    *reinterpret_cast<float4*>(out + (size_t)n * 128 + c * 4) = r;
}

extern "C" void kernel_launch(void* const* d_in, const int* in_sizes, int n_in,
                              void* d_out, int out_size, void* d_ws, size_t ws_size,
                              hipStream_t stream)
{
    const float* pos  = (const float*)d_in[0];
    const float* nf   = (const float*)d_in[1];
    const float* eain = (const float*)d_in[2];
    const int*   eidx = (const int*)  d_in[3];
    const float* encW = (const float*)d_in[4];
    const float* encb = (const float*)d_in[5];
    const float* neW1 = (const float*)d_in[6];
    const float* neb1 = (const float*)d_in[7];
    const float* neW2 = (const float*)d_in[8];
    const float* neb2 = (const float*)d_in[9];
    const float* eeW1 = (const float*)d_in[10];
    const float* eeb1 = (const float*)d_in[11];
    const float* eeW2 = (const float*)d_in[12];
    const float* eeb2 = (const float*)d_in[13];
    const float* reW1 = (const float*)d_in[14];
    const float* reb1 = (const float*)d_in[15];
    const float* reW2 = (const float*)d_in[16];
    const float* reb2 = (const float*)d_in[17];
    const float* fc1W = (const float*)d_in[18];
    const float* fc1b = (const float*)d_in[19];
    const float* fc2W = (const float*)d_in[20];
    const float* fc2b = (const float*)d_in[21];
    const float* lin0 = (const float*)d_in[22];
    const float* lin1 = (const float*)d_in[23];

    int N = in_sizes[0] / 3;
    int E = in_sizes[3] / 2;
    const int* srcI = eidx;
    const int* dstI = eidx + E;

    float* ws   = (float*)d_ws;
    float* h0   = ws;                               // N*16
    float* h1   = h0  + (size_t)N * 16;             // N*12
    float* eat  = h1  + (size_t)N * 12;             // E*16
    float* y1g  = eat + (size_t)E * 16;             // E*3
    float* cnt  = y1g + (size_t)E * 3;              // N
    float* acc0 = cnt + (size_t)N;                  // N*16
    float* acc1 = acc0 + (size_t)N * 16;            // N*12

    hipMemsetAsync(h1,  0, sizeof(float) * (size_t)N * 12, stream);
    hipMemsetAsync(cnt, 0, sizeof(float) * (size_t)N, stream);

    node_embed_kernel<<<(N + 255) / 256, 256, 0, stream>>>(
        nf, encW, encb, neW1, neb1, neW2, neb2, h0, N);
    edge_pre_kernel<<<(E + 255) / 256, 256, 0, stream>>>(
        pos, eain, srcI, dstI, eeW1, eeb1, eeW2, eeb2,
        reW1, reb1, reW2, reb2, eat, y1g, cnt, E);

    for (int i = 0; i < 2; ++i) {
        hipMemsetAsync(acc0, 0, sizeof(float) * (size_t)N * 16, stream);
        hipMemsetAsync(acc1, 0, sizeof(float) * (size_t)N * 12, stream);
        const float* fw1 = fc1W + (size_t)i * 48 * 64;
        const float* fb1 = fc1b + (size_t)i * 64;
        const float* fw2 = fc2W + (size_t)i * 64 * 416;
        const float* fb2 = fc2b + (size_t)i * 416;
        if (i == 0) {
            edge_tp_kernel<false><<<(E + 255) / 256, 256, 0, stream>>>(
                h0, h1, eat, y1g, srcI, dstI, fw1, fb1, fw2, fb2, acc0, acc1, E);
        } else {
            edge_tp_kernel<true><<<(E + 255) / 256, 256, 0, stream>>>(
                h0, h1, eat, y1g, srcI, dstI, fw1, fb1, fw2, fb2, acc0, acc1, E);
        }
        dim3 blk(32, 8);
        node_update_kernel<<<(N + 7) / 8, blk, 0, stream>>>(h0, h1, acc0, acc1, cnt, N);
    }

    final_kernel<<<((size_t)N * 32 + 255) / 256, 256, 0, stream>>>(
        h0, h1, lin0, lin1, (float*)d_out, N);
}

// Round 3
// 451.461 us; speedup vs baseline: 2.0491x; 2.0491x over previous
//
#include <hip/hip_runtime.h>
#include <math.h>

// ---- static config ----
// NS=16, NV=4, C=32, RDIM=32, FC_DIM=64, WNUM=416, L=2
#define SQRT3f     1.7320508075688772f
#define INV_SQRT3f 0.5773502691896258f
#define INV_SQRT2f 0.7071067811865476f
#define A0f        0.22360679774997896f   // 1/sqrt(16+4)
#define A1f        0.20412414523193150f   // 1/sqrt(16+8)

typedef __attribute__((ext_vector_type(8))) short bf16x8;
typedef __attribute__((ext_vector_type(4))) float f32x4;

__device__ __forceinline__ float4 ld4(const float* p) {
    return *reinterpret_cast<const float4*>(p);
}

__device__ __forceinline__ unsigned short f2bf(float x) {
    unsigned int u = __float_as_uint(x);
    u = (u + 0x7FFFu + ((u >> 16) & 1u)) >> 16;   // RNE
    return (unsigned short)u;
}

// out[16] = in[16] @ W[16,16] + b ; optional relu
template<bool RELU>
__device__ __forceinline__ void mm16x16(const float* in, const float* __restrict__ W,
                                        const float* __restrict__ b, float* out)
{
#pragma unroll
    for (int t = 0; t < 16; ++t) out[t] = b[t];
#pragma unroll
    for (int s = 0; s < 16; ++s) {
        float a = in[s];
#pragma unroll
        for (int q = 0; q < 4; ++q) {
            float4 w = ld4(W + s * 16 + q * 4);
            out[q*4+0] += a * w.x; out[q*4+1] += a * w.y;
            out[q*4+2] += a * w.z; out[q*4+3] += a * w.w;
        }
    }
    if (RELU) {
#pragma unroll
        for (int t = 0; t < 16; ++t) out[t] = fmaxf(out[t], 0.f);
    }
}

// h0[n] = MLP(node_feats[n] @ enc_W + enc_b)
__global__ __launch_bounds__(256)
void node_embed_kernel(const float* __restrict__ nf,
                       const float* __restrict__ encW, const float* __restrict__ encb,
                       const float* __restrict__ neW1, const float* __restrict__ neb1,
                       const float* __restrict__ neW2, const float* __restrict__ neb2,
                       float* __restrict__ h0, int N)
{
    int n = blockIdx.x * blockDim.x + threadIdx.x;
    if (n >= N) return;
    float x[16];
#pragma unroll
    for (int s = 0; s < 16; ++s) x[s] = encb[s];
    for (int i = 0; i < 64; ++i) {
        float a = nf[n * 64 + i];
#pragma unroll
        for (int q = 0; q < 4; ++q) {
            float4 w = ld4(encW + i * 16 + q * 4);
            x[q*4+0] += a * w.x; x[q*4+1] += a * w.y;
            x[q*4+2] += a * w.z; x[q*4+3] += a * w.w;
        }
    }
    float h[16], o[16];
    mm16x16<true >(x, neW1, neb1, h);
    mm16x16<false>(h, neW2, neb2, o);
#pragma unroll
    for (int j = 0; j < 16; ++j) h0[n * 16 + j] = o[j];
}

// per-edge: y1, edge_attr = MLP(edge_attr_in) + MLP(rbf(d)), cnt scatter
__global__ __launch_bounds__(256)
void edge_pre_kernel(const float* __restrict__ pos, const float* __restrict__ eain,
                     const int* __restrict__ srcI, const int* __restrict__ dstI,
                     const float* __restrict__ eeW1, const float* __restrict__ eeb1,
                     const float* __restrict__ eeW2, const float* __restrict__ eeb2,
                     const float* __restrict__ reW1, const float* __restrict__ reb1,
                     const float* __restrict__ reW2, const float* __restrict__ reb2,
                     float* __restrict__ eattr, float* __restrict__ y1g,
                     float* __restrict__ cnt, int E)
{
    int e = blockIdx.x * blockDim.x + threadIdx.x;
    if (e >= E) return;
    int s = srcI[e], d = dstI[e];
    float vx = pos[s*3+0] - pos[d*3+0];
    float vy = pos[s*3+1] - pos[d*3+1];
    float vz = pos[s*3+2] - pos[d*3+2];
    float dist = sqrtf(vx*vx + vy*vy + vz*vz);
    float inv = 1.f / fmaxf(dist, 1e-9f);
    y1g[e*3+0] = SQRT3f * vx * inv;
    y1g[e*3+1] = SQRT3f * vy * inv;
    y1g[e*3+2] = SQRT3f * vz * inv;

    const float step  = 12.0f / 31.0f;
    const float coeff = -0.5f / (step * step);
    float rbf[32];
#pragma unroll
    for (int j = 0; j < 32; ++j) {
        float t = dist - (float)j * step;
        rbf[j] = expf(coeff * t * t);
    }

    float ein[16];
#pragma unroll
    for (int j = 0; j < 16; ++j) ein[j] = eain[e * 16 + j];

    float t1[16], a1v[16];
    mm16x16<true >(ein, eeW1, eeb1, t1);
    mm16x16<false>(t1, eeW2, eeb2, a1v);

    float t2[16];
#pragma unroll
    for (int t = 0; t < 16; ++t) t2[t] = reb1[t];
    for (int j = 0; j < 32; ++j) {
        float a = rbf[j];
#pragma unroll
        for (int q = 0; q < 4; ++q) {
            float4 w = ld4(reW1 + j * 16 + q * 4);
            t2[q*4+0] += a * w.x; t2[q*4+1] += a * w.y;
            t2[q*4+2] += a * w.z; t2[q*4+3] += a * w.w;
        }
    }
#pragma unroll
    for (int t = 0; t < 16; ++t) t2[t] = fmaxf(t2[t], 0.f);
    float a2v[16];
    mm16x16<false>(t2, reW2, reb2, a2v);

#pragma unroll
    for (int j = 0; j < 16; ++j) eattr[e * 16 + j] = a1v[j] + a2v[j];

    atomicAdd(&cnt[s], 1.0f);
}

// pack fc2W (both layers) into MFMA B-fragment order, bf16:
// w2p[layer][nt][ks][lane][j] = W2[ks*32 + (lane>>4)*8 + j][nt*16 + (lane&15)]
__global__ void pack_w2_kernel(const float* __restrict__ fc2W, unsigned short* __restrict__ w2p)
{
    int idx = blockIdx.x * blockDim.x + threadIdx.x;
    if (idx >= 2 * 26 * 2 * 64) return;
    int lane  = idx & 63;
    int ks    = (idx >> 6) & 1;
    int nt    = (idx >> 7) % 26;
    int layer = idx / (26 * 2 * 64);
    const float* W = fc2W + (size_t)layer * 64 * 416;
    unsigned short* out = w2p + (size_t)layer * 26 * 2 * 64 * 8
                              + (size_t)((nt * 2 + ks) * 64 + lane) * 8;
    int k0 = ks * 32 + (lane >> 4) * 8;
    int c  = nt * 16 + (lane & 15);
#pragma unroll
    for (int j = 0; j < 8; ++j) out[j] = f2bf(W[(size_t)(k0 + j) * 416 + c]);
}

// per-layer: hid = relu(EA @ W1 + b1) -> bf16; also gather x0 = h0[dst],
// and (HAS_L1) x1 = h1[dst], dot = (x1.y1)/sqrt3, cr = (x1 x y1)/sqrt2.
template<bool HAS_L1>
__global__ __launch_bounds__(256)
void gemm1_kernel(const float* __restrict__ h0, const float* __restrict__ h1,
                  const float* __restrict__ eattr, const float* __restrict__ y1g,
                  const int* __restrict__ srcI, const int* __restrict__ dstI,
                  const float* __restrict__ fc1W, const float* __restrict__ fc1b,
                  unsigned short* __restrict__ hidb, float* __restrict__ x0g,
                  float* __restrict__ x1g, float* __restrict__ dotg,
                  float* __restrict__ crg, int E)
{
    __shared__ float w1s[48 * 64];
    __shared__ float b1s[64];
    for (int i = threadIdx.x; i < 48 * 64; i += 256) w1s[i] = fc1W[i];
    if (threadIdx.x < 64) b1s[threadIdx.x] = fc1b[threadIdx.x];
    __syncthreads();

    int e = blockIdx.x * 256 + threadIdx.x;
    if (e >= E) return;
    int s = srcI[e], d = dstI[e];

    float ea[48];
#pragma unroll
    for (int q = 0; q < 4; ++q) {
        float4 v = ld4(eattr + (size_t)e * 16 + q * 4);
        ea[q*4+0] = v.x; ea[q*4+1] = v.y; ea[q*4+2] = v.z; ea[q*4+3] = v.w;
    }
#pragma unroll
    for (int q = 0; q < 4; ++q) {
        float4 v = ld4(h0 + (size_t)s * 16 + q * 4);
        ea[16+q*4+0] = v.x; ea[16+q*4+1] = v.y; ea[16+q*4+2] = v.z; ea[16+q*4+3] = v.w;
    }
#pragma unroll
    for (int q = 0; q < 4; ++q) {
        float4 v = ld4(h0 + (size_t)d * 16 + q * 4);
        ea[32+q*4+0] = v.x; ea[32+q*4+1] = v.y; ea[32+q*4+2] = v.z; ea[32+q*4+3] = v.w;
        *reinterpret_cast<float4*>(x0g + (size_t)e * 16 + q * 4) = v;
    }

    if (HAS_L1) {
        float yv0 = y1g[e*3+0], yv1 = y1g[e*3+1], yv2 = y1g[e*3+2];
#pragma unroll
        for (int v = 0; v < 4; ++v) {
            float xa = h1[(size_t)d*12 + v*3 + 0];
            float xb = h1[(size_t)d*12 + v*3 + 1];
            float xc = h1[(size_t)d*12 + v*3 + 2];
            x1g[(size_t)e*12 + v*3 + 0] = xa;
            x1g[(size_t)e*12 + v*3 + 1] = xb;
            x1g[(size_t)e*12 + v*3 + 2] = xc;
            dotg[(size_t)e*4 + v] = (xa*yv0 + xb*yv1 + xc*yv2) * INV_SQRT3f;
            crg[(size_t)e*12 + v*3 + 0] = (xb*yv2 - xc*yv1) * INV_SQRT2f;
            crg[(size_t)e*12 + v*3 + 1] = (xc*yv0 - xa*yv2) * INV_SQRT2f;
            crg[(size_t)e*12 + v*3 + 2] = (xa*yv1 - xb*yv0) * INV_SQRT2f;
        }
    }

    float hid[64];
#pragma unroll
    for (int k = 0; k < 64; ++k) hid[k] = b1s[k];
    for (int j = 0; j < 48; ++j) {
        float a = ea[j];
#pragma unroll
        for (int q = 0; q < 16; ++q) {
            float4 w = *reinterpret_cast<const float4*>(&w1s[j * 64 + q * 4]);
            hid[q*4+0] += a * w.x; hid[q*4+1] += a * w.y;
            hid[q*4+2] += a * w.z; hid[q*4+3] += a * w.w;
        }
    }
#pragma unroll
    for (int g = 0; g < 8; ++g) {
        uint4 pk;
        unsigned int b0 = f2bf(fmaxf(hid[g*8+0], 0.f)), b1 = f2bf(fmaxf(hid[g*8+1], 0.f));
        unsigned int b2 = f2bf(fmaxf(hid[g*8+2], 0.f)), b3 = f2bf(fmaxf(hid[g*8+3], 0.f));
        unsigned int b4 = f2bf(fmaxf(hid[g*8+4], 0.f)), b5 = f2bf(fmaxf(hid[g*8+5], 0.f));
        unsigned int b6 = f2bf(fmaxf(hid[g*8+6], 0.f)), b7 = f2bf(fmaxf(hid[g*8+7], 0.f));
        pk.x = b0 | (b1 << 16); pk.y = b2 | (b3 << 16);
        pk.z = b4 | (b5 << 16); pk.w = b6 | (b7 << 16);
        reinterpret_cast<uint4*>(hidb + (size_t)e * 64)[g] = pk;
    }
}

// GEMM2 (MFMA) + fused TP epilogue + atomic scatter.
// Block = 4 waves; wave handles 64 edges as 4 M-subtiles of 16.
// P[e, col] tiles produced per nt (26 N-tiles of 16), consumed immediately:
//   nt 0..15  w00 : o0[e,o=col]   += x0[e,nt] * P
//   nt 16..19 w011: t011[e,col&3] += x0[e,(nt-16)*4+(col>>2)] * P
//   nt 20     w101: o1[e,col&3,d] += x1[e,col>>2,d] * P
//   nt 21..24 w110: o0[e,o=col]   += dot[e,nt-21] * P
//   nt 25     w111: o1[e,col&3,d] += cr[e,col>>2,d] * P
template<bool HAS_L1>
__global__ __launch_bounds__(256)
void gemm2_tp_kernel(const unsigned short* __restrict__ hidb,
                     const unsigned short* __restrict__ w2p,
                     const float* __restrict__ b2,
                     const float* __restrict__ x0g,
                     const float* __restrict__ x1g,
                     const float* __restrict__ dotg,
                     const float* __restrict__ crg,
                     const float* __restrict__ y1g,
                     const int* __restrict__ srcI,
                     float* __restrict__ acc0, float* __restrict__ acc1, int E)
{
    int wave = threadIdx.x >> 6;
    int lane = threadIdx.x & 63;
    int ebase = blockIdx.x * 256 + wave * 64;
    int col = lane & 15;       // N-col in tile; also A-fragment row
    int grp = lane >> 4;       // k-chunk; D-fragment row group

    // A fragments: lane holds hid[ebase+m*16+col][grp*8 + ks*32 .. +7]
    bf16x8 a[4][2];
#pragma unroll
    for (int m = 0; m < 4; ++m) {
        const bf16x8* ap = reinterpret_cast<const bf16x8*>(
            hidb + (size_t)(ebase + m * 16 + col) * 64 + grp * 8);
        a[m][0] = ap[0];
        a[m][1] = ap[4];       // +32 shorts
    }

    float o0a[4][4];
    float t011p[4][4];
    float o1p[4][4][3];
#pragma unroll
    for (int m = 0; m < 4; ++m)
#pragma unroll
        for (int r = 0; r < 4; ++r) {
            o0a[m][r] = 0.f; t011p[m][r] = 0.f;
            o1p[m][r][0] = 0.f; o1p[m][r][1] = 0.f; o1p[m][r][2] = 0.f;
        }

    const int NT = HAS_L1 ? 26 : 20;
    for (int nt = 0; nt < NT; ++nt) {
        const bf16x8* bp = reinterpret_cast<const bf16x8*>(
            w2p + (size_t)(nt * 2 * 64 + lane) * 8);
        bf16x8 b0 = bp[0];
        bf16x8 b1 = bp[64];    // next ks: +64*8 shorts
        float bias = b2[nt * 16 + col];
#pragma unroll
        for (int m = 0; m < 4; ++m) {
            f32x4 acc = {0.f, 0.f, 0.f, 0.f};
            acc = __builtin_amdgcn_mfma_f32_16x16x32_bf16(a[m][0], b0, acc, 0, 0, 0);
            acc = __builtin_amdgcn_mfma_f32_16x16x32_bf16(a[m][1], b1, acc, 0, 0, 0);
            int e0 = ebase + m * 16 + grp * 4;
            if (nt < 16) {
#pragma unroll
                for (int r = 0; r < 4; ++r) {
                    float p = acc[r] + bias;
                    o0a[m][r] += x0g[(size_t)(e0 + r) * 16 + nt] * p;
                }
            } else if (nt < 20) {
                int n = (nt - 16) * 4 + (col >> 2);
#pragma unroll
                for (int r = 0; r < 4; ++r) {
                    float p = acc[r] + bias;
                    t011p[m][r] += x0g[(size_t)(e0 + r) * 16 + n] * p;
                }
            } else if (nt == 20) {
                int n = col >> 2;
#pragma unroll
                for (int r = 0; r < 4; ++r) {
                    float p = acc[r] + bias;
#pragma unroll
                    for (int d = 0; d < 3; ++d)
                        o1p[m][r][d] += x1g[(size_t)(e0 + r) * 12 + n * 3 + d] * p;
                }
            } else if (nt < 25) {
                int n = nt - 21;
#pragma unroll
                for (int r = 0; r < 4; ++r) {
                    float p = acc[r] + bias;
                    o0a[m][r] += dotg[(size_t)(e0 + r) * 4 + n] * p;
                }
            } else {
                int n = col >> 2;
#pragma unroll
                for (int r = 0; r < 4; ++r) {
                    float p = acc[r] + bias;
#pragma unroll
                    for (int d = 0; d < 3; ++d)
                        o1p[m][r][d] += crg[(size_t)(e0 + r) * 12 + n * 3 + d] * p;
                }
            }
        }
    }

    // epilogue: reduce 4-lane partials (lanes col, col^4, col^8, col^12 share
    // the same o = col&3 class and the same edge), add t011*y1, scatter.
#pragma unroll
    for (int m = 0; m < 4; ++m) {
        int e0 = ebase + m * 16 + grp * 4;
#pragma unroll
        for (int r = 0; r < 4; ++r) {
            int e = e0 + r;
            int sN = srcI[e];
            float t = t011p[m][r];
            t += __shfl_xor(t, 4);
            t += __shfl_xor(t, 8);
            float o1v[3];
#pragma unroll
            for (int d = 0; d < 3; ++d) {
                float v = o1p[m][r][d];
                v += __shfl_xor(v, 4);
                v += __shfl_xor(v, 8);
                o1v[d] = v + t * y1g[(size_t)e * 3 + d];
            }
            atomicAdd(&acc0[(size_t)sN * 16 + col], A0f * o0a[m][r]);
            if (col < 4) {
#pragma unroll
                for (int d = 0; d < 3; ++d)
                    atomicAdd(&acc1[(size_t)sN * 12 + col * 3 + d], A1f * o1v[d]);
            }
        }
    }
}

// residual update: h += acc / max(cnt,1)   (the single scatter-MEAN divide)
__global__ void node_update_kernel(float* __restrict__ h0, float* __restrict__ h1,
                                   const float* __restrict__ acc0, const float* __restrict__ acc1,
                                   const float* __restrict__ cnt, int N)
{
    int j = threadIdx.x;                       // 0..31 (use 0..27)
    int n = blockIdx.x * blockDim.y + threadIdx.y;
    if (n >= N || j >= 28) return;
    float invc = 1.f / fmaxf(cnt[n], 1.f);
    if (j < 16) h0[n * 16 + j] += acc0[n * 16 + j] * invc;
    else {
        int m = j - 16;
        h1[n * 12 + m] += acc1[n * 12 + m] * invc;
    }
}

// final o3.Linear + sorter: out[n, c*4+0]=f0[n,c]; out[n, c*4+1+m]=f1[n,c,m]
__global__ __launch_bounds__(256)
void final_kernel(const float* __restrict__ h0, const float* __restrict__ h1,
                  const float* __restrict__ lin0, const float* __restrict__ lin1,
                  float* __restrict__ out, int N)
{
    int i = blockIdx.x * blockDim.x + threadIdx.x;
    if (i >= N * 32) return;
    int n = i >> 5, c = i & 31;
    float f0 = 0.f;
#pragma unroll
    for (int s = 0; s < 16; ++s) f0 += h0[n * 16 + s] * lin0[s * 32 + c];
    f0 *= 0.25f;                                // 1/sqrt(16)
    float f1x = 0.f, f1y = 0.f, f1z = 0.f;
#pragma unroll
    for (int v = 0; v < 4; ++v) {
        float w = lin1[v * 32 + c];
        f1x += h1[n * 12 + v * 3 + 0] * w;
        f1y += h1[n * 12 + v * 3 + 1] * w;
        f1z += h1[n * 12 + v * 3 + 2] * w;
    }
    float4 r;
    r.x = f0;
    r.y = f1x * 0.5f;                           // 1/sqrt(4)
    r.z = f1y * 0.5f;
    r.w = f1z * 0.5f;
    *reinterpret_cast<float4*>(out + (size_t)n * 128 + c * 4) = r;
}

extern "C" void kernel_launch(void* const* d_in, const int* in_sizes, int n_in,
                              void* d_out, int out_size, void* d_ws, size_t ws_size,
                              hipStream_t stream)
{
    const float* pos  = (const float*)d_in[0];
    const float* nf   = (const float*)d_in[1];
    const float* eain = (const float*)d_in[2];
    const int*   eidx = (const int*)  d_in[3];
    const float* encW = (const float*)d_in[4];
    const float* encb = (const float*)d_in[5];
    const float* neW1 = (const float*)d_in[6];
    const float* neb1 = (const float*)d_in[7];
    const float* neW2 = (const float*)d_in[8];
    const float* neb2 = (const float*)d_in[9];
    const float* eeW1 = (const float*)d_in[10];
    const float* eeb1 = (const float*)d_in[11];
    const float* eeW2 = (const float*)d_in[12];
    const float* eeb2 = (const float*)d_in[13];
    const float* reW1 = (const float*)d_in[14];
    const float* reb1 = (const float*)d_in[15];
    const float* reW2 = (const float*)d_in[16];
    const float* reb2 = (const float*)d_in[17];
    const float* fc1W = (const float*)d_in[18];
    const float* fc1b = (const float*)d_in[19];
    const float* fc2W = (const float*)d_in[20];
    const float* fc2b = (const float*)d_in[21];
    const float* lin0 = (const float*)d_in[22];
    const float* lin1 = (const float*)d_in[23];

    int N = in_sizes[0] / 3;
    int E = in_sizes[3] / 2;
    const int* srcI = eidx;
    const int* dstI = eidx + E;

    float* ws = (float*)d_ws;
    size_t o = 0;
    float* h0   = ws + o; o += (size_t)N * 16;
    float* h1   = ws + o; o += (size_t)N * 12;
    float* eat  = ws + o; o += (size_t)E * 16;
    float* y1g  = ws + o; o += (size_t)E * 3;
    float* cnt  = ws + o; o += (size_t)N;
    float* acc0 = ws + o; o += (size_t)N * 16;
    float* acc1 = ws + o; o += (size_t)N * 12;
    float* x0g  = ws + o; o += (size_t)E * 16;
    float* x1g  = ws + o; o += (size_t)E * 12;
    float* dotg = ws + o; o += (size_t)E * 4;
    float* crg  = ws + o; o += (size_t)E * 12;
    unsigned short* hidb = (unsigned short*)(ws + o); o += (size_t)E * 32;  // E*64 bf16
    unsigned short* w2p  = (unsigned short*)(ws + o); o += 26624;           // 2*26624 bf16

    hipMemsetAsync(h1,  0, sizeof(float) * (size_t)N * 12, stream);
    hipMemsetAsync(cnt, 0, sizeof(float) * (size_t)N, stream);

    pack_w2_kernel<<<26, 256, 0, stream>>>(fc2W, w2p);
    node_embed_kernel<<<(N + 255) / 256, 256, 0, stream>>>(
        nf, encW, encb, neW1, neb1, neW2, neb2, h0, N);
    edge_pre_kernel<<<(E + 255) / 256, 256, 0, stream>>>(
        pos, eain, srcI, dstI, eeW1, eeb1, eeW2, eeb2,
        reW1, reb1, reW2, reb2, eat, y1g, cnt, E);

    for (int i = 0; i < 2; ++i) {
        hipMemsetAsync(acc0, 0, sizeof(float) * (size_t)N * 16, stream);
        hipMemsetAsync(acc1, 0, sizeof(float) * (size_t)N * 12, stream);
        const float* fw1 = fc1W + (size_t)i * 48 * 64;
        const float* fb1 = fc1b + (size_t)i * 64;
        const float* fb2 = fc2b + (size_t)i * 416;
        const unsigned short* w2pi = w2p + (size_t)i * 26 * 2 * 64 * 8;
        if (i == 0) {
            gemm1_kernel<false><<<(E + 255) / 256, 256, 0, stream>>>(
                h0, h1, eat, y1g, srcI, dstI, fw1, fb1,
                hidb, x0g, x1g, dotg, crg, E);
            gemm2_tp_kernel<false><<<E / 256, 256, 0, stream>>>(
                hidb, w2pi, fb2, x0g, x1g, dotg, crg, y1g, srcI, acc0, acc1, E);
        } else {
            gemm1_kernel<true><<<(E + 255) / 256, 256, 0, stream>>>(
                h0, h1, eat, y1g, srcI, dstI, fw1, fb1,
                hidb, x0g, x1g, dotg, crg, E);
            gemm2_tp_kernel<true><<<E / 256, 256, 0, stream>>>(
                hidb, w2pi, fb2, x0g, x1g, dotg, crg, y1g, srcI, acc0, acc1, E);
        }
        dim3 blk(32, 8);
        node_update_kernel<<<(N + 7) / 8, blk, 0, stream>>>(h0, h1, acc0, acc1, cnt, N);
    }

    final_kernel<<<((size_t)N * 32 + 255) / 256, 256, 0, stream>>>(
        h0, h1, lin0, lin1, (float*)d_out, N);
}